// Round 18
// baseline (636.622 us; speedup 1.0000x reference)
//
#include <hip/hip_runtime.h>
#include <cstdint>
#include <cstddef>

#define DIMX 1024
#define HID  1536
#define BB   4
#define TT   4096
#define MM   (BB*TT)       // 16384 rows
#define NPROJ (2*HID)      // 3072
#define NC   256           // scan chunks
#define CH   16            // chunk length (NC*CH == TT)
#define HB8  (HID/8)       // 192

typedef _Float16 f16x8 __attribute__((ext_vector_type(8)));
typedef float    f32x4 __attribute__((ext_vector_type(4)));

#define GLOAD_LDS16(g, l) \
  __builtin_amdgcn_global_load_lds((__attribute__((address_space(1))) const void*)(g), \
                                   (__attribute__((address_space(3))) void*)(l), 16, 0, 0)

__device__ __forceinline__ float fast_sigmoid(float z) {
  return 1.f / (1.f + __expf(-z));
}
__device__ __forceinline__ float fast_erf(float x) {
  float ax = fabsf(x);
  float t = 1.f / (1.f + 0.3275911f * ax);
  float p = t * (0.254829592f + t * (-0.284496736f + t * (1.421413741f +
            t * (-1.453152027f + t * 1.061405429f))));
  float r = 1.f - p * __expf(-ax * ax);
  return copysignf(r, x);
}

// ------- fused convert fp32 -> fp16 for all 5 tensors, one dispatch -------
__global__ void k_cvt_all(const float* __restrict__ x,  const float* __restrict__ pw,
                          const float* __restrict__ gw, const float* __restrict__ iw,
                          const float* __restrict__ ow,
                          _Float16* __restrict__ xb, _Float16* __restrict__ pwb,
                          _Float16* __restrict__ gwb, _Float16* __restrict__ owb) {
  long i = (long)blockIdx.x * blockDim.x + threadIdx.x;
  const float* src; _Float16* dst; long o;
  if      (i < 4194304) { src = x;  dst = xb;  o = i; }
  else if (i < 4980736) { src = pw; dst = pwb; o = i - 4194304; }
  else if (i < 5570560) { src = gw; dst = gwb; o = i - 4980736; }
  else if (i < 6160384) { src = iw; dst = gwb + 2359296; o = i - 5570560; }
  else if (i < 6553600) { src = ow; dst = owb; o = i - 6160384; }
  else return;
  float4 v = ((const float4*)src)[o];
  union { _Float16 h[4]; uint64_t u; } r;
  r.h[0] = (_Float16)v.x; r.h[1] = (_Float16)v.y;
  r.h[2] = (_Float16)v.z; r.h[3] = (_Float16)v.w;
  ((uint64_t*)dst)[o] = r.u;
}

// ================= 256x256 8-phase GEMM (r4-verified core) =================
// C[M,N] = A[M,K] * B[N,K]^T, fp16 in. 8 waves (2M x 4N), wave out 128x64
// (8m x 4n frags of 16x16x32). Interleaved m-map: row(m) = m*32 + wr*16.
// LDS 128KB: 2 dbuf x (A 32KB + B 32KB). 1.5x fewer LDS-port bytes/FLOP
// than 128^2 (port ceiling ~59% MfmaUtil vs 40%). Per phase:
// {ds_read subtile | stage 1 half-tile} BAR lgkm0 16xMFMA [vmcnt(6)@ph4/8] BAR.
// T2 swizzle: physical 16B-granule = logical ^ (row&7); linear LDS dest,
// inverse-swizzled global source, swizzled ds_read (rule #21).
// Two-level L2 map (GRP2=4): 4 A-tiles (3MB) + B panel (768KB) <= 4MB L2.
// MODE 1: col<HID -> gelu -> Ch; col>=HID -> raw fp16 -> Ch2
// MODE 5: col<HID -> s = 8*softplus(fl)*sigmoid(v+bias) -> Ch;
//         col>=HID -> inp = sigmoid(v+bias2)            -> Ch2
// MODE 4: plain fp32 -> Cf
#define BM 256
#define BN 256
#define BK 64
#define GRP2 4

#define MFMA16(a, b, c) __builtin_amdgcn_mfma_f32_16x16x32_f16(a, b, c, 0, 0, 0)

#define PHASE(P, STAGE_STMT, WAIT_STMT)                                      \
  {                                                                          \
    const char* sa_ = (const char*)sA[(P) > 4 ? 1 : 0];                      \
    const char* sb_ = (const char*)sB[(P) > 4 ? 1 : 0];                      \
    constexpr int m0_ = (((P) - 1) & 3) * 2;                                 \
    if constexpr ((((P) - 1) & 3) == 0) {                                    \
      _Pragma("unroll")                                                      \
      for (int n = 0; n < 4; ++n) {                                          \
        bf[n][0] = *(const f16x8*)(sb_ + Bbase + n * 8192 + pg0);            \
        bf[n][1] = *(const f16x8*)(sb_ + Bbase + n * 8192 + pg1);            \
      }                                                                      \
    }                                                                        \
    f16x8 a00 = *(const f16x8*)(sa_ + Abase + (m0_    ) * 4096 + pg0);       \
    f16x8 a01 = *(const f16x8*)(sa_ + Abase + (m0_    ) * 4096 + pg1);       \
    f16x8 a10 = *(const f16x8*)(sa_ + Abase + (m0_ + 1) * 4096 + pg0);       \
    f16x8 a11 = *(const f16x8*)(sa_ + Abase + (m0_ + 1) * 4096 + pg1);       \
    STAGE_STMT;                                                              \
    __builtin_amdgcn_s_barrier();                                            \
    asm volatile("s_waitcnt lgkmcnt(0)" ::: "memory");                       \
    __builtin_amdgcn_sched_barrier(0);                                       \
    __builtin_amdgcn_s_setprio(1);                                           \
    _Pragma("unroll")                                                        \
    for (int n = 0; n < 4; ++n) {                                            \
      acc[m0_][n]     = MFMA16(a00, bf[n][0], acc[m0_][n]);                  \
      acc[m0_][n]     = MFMA16(a01, bf[n][1], acc[m0_][n]);                  \
      acc[m0_ + 1][n] = MFMA16(a10, bf[n][0], acc[m0_ + 1][n]);              \
      acc[m0_ + 1][n] = MFMA16(a11, bf[n][1], acc[m0_ + 1][n]);              \
    }                                                                        \
    __builtin_amdgcn_s_setprio(0);                                           \
    WAIT_STMT;                                                               \
    __builtin_amdgcn_s_barrier();                                            \
    __builtin_amdgcn_sched_barrier(0);                                       \
  }

template<int MODE>
__global__ __launch_bounds__(512, 2) void k_gemm(
    const _Float16* __restrict__ A, const _Float16* __restrict__ B,
    float* __restrict__ Cf, _Float16* __restrict__ Ch, _Float16* __restrict__ Ch2,
    const float* __restrict__ bias, const float* __restrict__ bias2,
    const float* __restrict__ fl,
    int M, int N, int K, int gridN)
{
  __shared__ __align__(16) _Float16 sA[2][BM * BK];   // 2 x 32 KB
  __shared__ __align__(16) _Float16 sB[2][BN * BK];   // 2 x 32 KB (128 KB total)
  const int tid  = threadIdx.x;
  const int wave = tid >> 6;
  const int lane = tid & 63;
  const int wr = wave >> 2, wc = wave & 3;

  // two-level L2 map: XCD band + GRP2-group sweep (bijective: nwg%8==0,
  // rpx%GRP2==0 for all shapes: GEMM1/5 rpx=8, GEMM4 rpx=8)
  const int nwg = gridDim.x;
  const int bid = blockIdx.x;
  const int xcd = bid & 7;
  const int loc = bid >> 3;
  const int rpx = (nwg >> 3) / gridN;
  const int sg  = loc / (GRP2 * gridN);
  const int rem = loc % (GRP2 * gridN);
  const int mg  = rem % GRP2;                // m fast
  const int nn  = rem / GRP2;                // n slow
  const long rowA = (long)(xcd * rpx + sg * GRP2 + mg) * BM;
  const long rowB = (long)nn * BN;

  const int r8  = lane >> 3;
  const int gsw = ((lane & 7) ^ r8) * 8;    // inverse-swizzled source granule

  auto stA = [&](int buf, int h, int kt) {
    const _Float16* g = A + (rowA + h * 128 + wave * 8 + r8) * (long)K + kt + gsw;
    GLOAD_LDS16(g,                &sA[buf][(h * 128      + wave * 8) * 64]);
    GLOAD_LDS16(g + 64 * (long)K, &sA[buf][(h * 128 + 64 + wave * 8) * 64]);
  };
  auto stB = [&](int buf, int h, int kt) {
    const _Float16* g = B + (rowB + h * 128 + wave * 8 + r8) * (long)K + kt + gsw;
    GLOAD_LDS16(g,                &sB[buf][(h * 128      + wave * 8) * 64]);
    GLOAD_LDS16(g + 64 * (long)K, &sB[buf][(h * 128 + 64 + wave * 8) * 64]);
  };

  const int frow = lane & 15;
  const int pg0  = ((lane >> 4) ^ (frow & 7)) << 4;   // swizzled read granule, kk=0
  const int pg1  = pg0 ^ 64;                          // kk=1
  const int Abase = (wr * 16 + frow) * 128;
  const int Bbase = (wc * 16 + frow) * 128;

  const int nt    = K / BK;   // 16 or 24 (even)
  const int nIter = nt / 2;

  // prologue: tile0 fully + tile1 {Bh0,Bh1,Ah0} = 14 loads; vmcnt(6) -> tile0 landed
  stB(0, 0, 0);  stB(0, 1, 0);  stA(0, 0, 0);  stA(0, 1, 0);
  stB(1, 0, BK); stB(1, 1, BK); stA(1, 0, BK);
  asm volatile("s_waitcnt vmcnt(6)" ::: "memory");
  __builtin_amdgcn_s_barrier();
  __builtin_amdgcn_sched_barrier(0);

  f32x4 acc[8][4] = {};
  f16x8 bf[4][2];

  for (int it = 0; it < nIter; ++it) {
    const bool nl  = (it + 1 < nIter);
    const int kt1 = (2 * it + 1) * BK;
    const int ke  = (2 * it + 2) * BK;
    const int ko  = (2 * it + 3) * BK;
    PHASE(1, { stA(1, 1, kt1); }, {});
    PHASE(2, { if (nl) stB(0, 0, ke); }, {});
    PHASE(3, { if (nl) stB(0, 1, ke); }, {});
    PHASE(4, { if (nl) stA(0, 0, ke); },
             { if (nl) { asm volatile("s_waitcnt vmcnt(6)" ::: "memory"); }
               else    { asm volatile("s_waitcnt vmcnt(0)" ::: "memory"); } });
    PHASE(5, { if (nl) stA(0, 1, ke); }, {});
    PHASE(6, { if (nl) stB(1, 0, ko); }, {});
    PHASE(7, { if (nl) stB(1, 1, ko); }, {});
    PHASE(8, { if (nl) stA(1, 0, ko); },
             { if (nl) { asm volatile("s_waitcnt vmcnt(6)" ::: "memory"); }
               else    { asm volatile("s_waitcnt vmcnt(0)" ::: "memory"); } });
  }

  // ---------------- epilogue (no DMA outstanding) ----------------
  const int q4   = (lane >> 4) * 4;
  const int ccol = lane & 15;

  float bn[4], spn[4];
  if (MODE == 5) {
    #pragma unroll
    for (int n = 0; n < 4; ++n) {
      long c = rowB + n * 64 + wc * 16 + ccol;
      if (c < HID) {
        bn[n]  = bias[c];
        spn[n] = 8.f * log1pf(__expf(fl[c]));
      } else {
        bn[n]  = bias2[c - HID];
        spn[n] = 0.f;
      }
    }
  }

  #pragma unroll
  for (int m = 0; m < 8; ++m)
    #pragma unroll
    for (int n = 0; n < 4; ++n) {
      long r0 = rowA + m * 32 + wr * 16 + q4;
      long c  = rowB + n * 64 + wc * 16 + ccol;
      #pragma unroll
      for (int r = 0; r < 4; ++r) {
        float v = acc[m][n][r];
        long rr = r0 + r;
        if (MODE == 1) {
          if (c < HID) {
            float ge = 0.5f * v * (1.f + fast_erf(v * 0.70710678118654752f));
            Ch[rr * (long)HID + c] = (_Float16)ge;
          } else {
            Ch2[rr * (long)HID + (c - HID)] = (_Float16)v;
          }
        } else if (MODE == 5) {
          float sig = fast_sigmoid(v + bn[n]);
          if (c < HID) Ch[rr * (long)HID + c] = (_Float16)(spn[n] * sig);
          else         Ch2[rr * (long)HID + (c - HID)] = (_Float16)sig;
        } else {
          Cf[rr * (long)N + c] = v;
        }
      }
    }
}

// ------- depthwise causal conv K=4: 4 t-steps x 8 channels per thread -----
__global__ void k_conv(const _Float16* __restrict__ xhb, const float* __restrict__ cw,
                       const float* __restrict__ cb, _Float16* __restrict__ xch) {
  long i = (long)blockIdx.x * blockDim.x + threadIdx.x;   // over (MM/4)*HB8
  if (i >= (long)(MM / 4) * HB8) return;
  const int hb = (int)(i % HB8);
  const long m4 = i / HB8;
  const long m0 = m4 * 4;
  const int t0 = (int)(m0 % TT);
  const int h0 = hb * 8;

  f16x8 rows[7];
  #pragma unroll
  for (int j = 0; j < 7; ++j) {
    if (t0 + j - 3 >= 0) {
      rows[j] = *(const f16x8*)&xhb[(m0 + j - 3) * (long)HID + h0];
    } else {
      #pragma unroll
      for (int q = 0; q < 8; ++q) rows[j][q] = (_Float16)0.f;
    }
  }
  float wgt[4][8], bias[8];
  #pragma unroll
  for (int q = 0; q < 8; ++q) {
    bias[q] = cb[h0 + q];
    #pragma unroll
    for (int k = 0; k < 4; ++k) wgt[k][q] = cw[(h0 + q) * 4 + k];
  }
  #pragma unroll
  for (int tt = 0; tt < 4; ++tt) {
    f16x8 o;
    #pragma unroll
    for (int q = 0; q < 8; ++q) {
      float acc = bias[q];
      #pragma unroll
      for (int k = 0; k < 4; ++k) acc += (float)rows[tt + k][q] * wgt[k][q];
      o[q] = (_Float16)acc;
    }
    *(f16x8*)&xch[(m0 + tt) * (long)HID + h0] = o;
  }
}

// ---------------- scan phase 1: per-chunk aggregates, 8 ch/thread ------
__global__ void k_scan1(const _Float16* __restrict__ sbuf, const _Float16* __restrict__ ibuf,
                        const _Float16* __restrict__ xcv,
                        float* __restrict__ Ac, float* __restrict__ Bc) {
  long i = (long)blockIdx.x * blockDim.x + threadIdx.x;   // over BB*NC*HB8
  if (i >= (long)BB * NC * HB8) return;
  const int hb = (int)(i % HB8);
  const long bc = i / HB8;
  const int c = (int)(bc % NC);
  const int b = (int)(bc / NC);
  const long base = ((long)b * TT + (long)c * CH) * HID + hb * 8;
  float A[8], Bv[8];
  #pragma unroll
  for (int j = 0; j < 8; ++j) { A[j] = 1.f; Bv[j] = 0.f; }
  #pragma unroll 4
  for (int t = 0; t < CH; ++t) {
    long idx = base + (long)t * HID;
    f16x8 sv = *(const f16x8*)&sbuf[idx];
    f16x8 iv = *(const f16x8*)&ibuf[idx];
    f16x8 xv = *(const f16x8*)&xcv[idx];
    #pragma unroll
    for (int j = 0; j < 8; ++j) {
      float a = __expf(-(float)sv[j]);
      float beta = sqrtf(1.f - a * a + 1e-6f);
      float x = beta * (float)iv[j] * (float)xv[j];
      A[j] *= a;
      Bv[j] = a * Bv[j] + x;
    }
  }
  long o = ((long)b * NC + c) * HID + hb * 8;
  #pragma unroll
  for (int j = 0; j < 8; ++j) { Ac[o + j] = A[j]; Bc[o + j] = Bv[j]; }
}

// ---------------- scan phase 2: prefix over chunks ---------------------
__global__ void k_scan2(const float* __restrict__ Ac, const float* __restrict__ Bc,
                        float* __restrict__ carry) {
  int i = blockIdx.x * blockDim.x + threadIdx.x;          // over BB*HID
  if (i >= BB * HID) return;
  const int h = i % HID;
  const int b = i / HID;
  float cv = 0.f;
  #pragma unroll 8
  for (int c = 0; c < NC; ++c) {
    long idx = ((long)b * NC + c) * HID + h;
    carry[idx] = cv;
    cv = Ac[idx] * cv + Bc[idx];
  }
}

// -------- scan phase 3 + gelu-gate multiply, 8 ch/thread ----------------
__global__ void k_scan3(const _Float16* __restrict__ sbuf, const _Float16* __restrict__ ibuf,
                        const _Float16* __restrict__ xcv, const float* __restrict__ carry,
                        const _Float16* __restrict__ geluG, _Float16* __restrict__ vb) {
  long i = (long)blockIdx.x * blockDim.x + threadIdx.x;   // over BB*NC*HB8
  if (i >= (long)BB * NC * HB8) return;
  const int hb = (int)(i % HB8);
  const long bc = i / HB8;
  const int c = (int)(bc % NC);
  const int b = (int)(bc / NC);
  const long base = ((long)b * TT + (long)c * CH) * HID + hb * 8;
  const long o = ((long)b * NC + c) * HID + hb * 8;
  float hv[8];
  #pragma unroll
  for (int j = 0; j < 8; ++j) hv[j] = carry[o + j];
  #pragma unroll 4
  for (int t = 0; t < CH; ++t) {
    long idx = base + (long)t * HID;
    f16x8 sv = *(const f16x8*)&sbuf[idx];
    f16x8 iv = *(const f16x8*)&ibuf[idx];
    f16x8 xv = *(const f16x8*)&xcv[idx];
    f16x8 gv = *(const f16x8*)&geluG[idx];
    f16x8 ov;
    #pragma unroll
    for (int j = 0; j < 8; ++j) {
      float a = __expf(-(float)sv[j]);
      float beta = sqrtf(1.f - a * a + 1e-6f);
      float x = beta * (float)iv[j] * (float)xv[j];
      hv[j] = a * hv[j] + x;
      ov[j] = (_Float16)((float)gv[j] * hv[j]);
    }
    *(f16x8*)&vb[idx] = ov;
  }
}

extern "C" void kernel_launch(void* const* d_in, const int* in_sizes, int n_in,
                              void* d_out, int out_size, void* d_ws, size_t ws_size,
                              hipStream_t stream) {
  const float* x      = (const float*)d_in[0];
  const float* proj_w = (const float*)d_in[1];
  const float* conv_w = (const float*)d_in[2];
  const float* conv_b = (const float*)d_in[3];
  const float* ip_w   = (const float*)d_in[4];
  const float* ip_b   = (const float*)d_in[5];
  const float* gp_w   = (const float*)d_in[6];
  const float* gp_b   = (const float*)d_in[7];
  const float* fl     = (const float*)d_in[8];
  const float* out_w  = (const float*)d_in[9];
  float* out = (float*)d_out;
  (void)in_sizes; (void)n_in; (void)out_size;

  // ---- workspace layout: 239.1 MB (< 261.1 MB proven available) ----
  const size_t SZ_PW   = (size_t)NPROJ * DIMX * 2;        //  6,291,456
  const size_t SZ_GW   = (size_t)NPROJ * HID * 2;         //  9,437,184
  const size_t SZ_OW   = (size_t)DIMX * HID * 2;          //  3,145,728
  const size_t SZ_MH16 = (size_t)MM * HID * 2;            // 50,331,648 (48 MiB)
  const size_t SZ_SC   = (size_t)BB * NC * HID * 4;       //  6,291,456
  const size_t NEED = SZ_PW + SZ_GW + SZ_OW + 4 * SZ_MH16 + 3 * SZ_SC; // 239,075,328
  if (ws_size < NEED) return;

  char* ws = (char*)d_ws;
  _Float16* pwb   = (_Float16*)(ws);                       // proj weights fp16
  _Float16* gwb   = (_Float16*)(ws + SZ_PW);               // [gp;ip] weights fp16
  _Float16* owb   = (_Float16*)(ws + SZ_PW + SZ_GW);       // out weights fp16
  char* ws2 = ws + SZ_PW + SZ_GW + SZ_OW;
  _Float16* geluG = (_Float16*)(ws2);                      // gelu(gate) fp16
  _Float16* xhb   = (_Float16*)(ws2 + SZ_MH16);            // xh fp16 -> later vb
  _Float16* xch   = (_Float16*)(ws2 + 2 * SZ_MH16);        // conv out fp16 (xc)
  _Float16* ibuf  = (_Float16*)(ws2 + 3 * SZ_MH16);        // inp sigmoid fp16
  float*    Ac    = (float*)(ws2 + 4 * SZ_MH16);
  float*    Bc    = (float*)(ws2 + 4 * SZ_MH16 + SZ_SC);
  float*    carry = (float*)(ws2 + 4 * SZ_MH16 + 2 * SZ_SC);

  // d_out aliasing (64 MiB): xb fp16 [0,32M) dead after GEMM1;
  // sbuf fp16 [0,48M) live GEMM5..scan3; GEMM4 overwrites all of d_out last.
  _Float16* xb    = (_Float16*)d_out;
  _Float16* sbuf  = (_Float16*)d_out;                      // s = 8*softplus*rec

  const int THR = 256;
  auto blocks = [&](long n) { return dim3((unsigned)((n + THR - 1) / THR)); };

  // one fused convert: x, proj_w, gp_w, ip_w, out_w -> fp16
  k_cvt_all<<<dim3(25600), THR, 0, stream>>>(x, proj_w, gp_w, ip_w, out_w,
                                             xb, pwb, gwb, owb);

  // GEMM1: [M,3072] = xb @ proj_w^T ; epilogue: gelu(gate) / raw xh split
  k_gemm<1><<<dim3((MM / BM) * (NPROJ / BN)), 512, 0, stream>>>(
      xb, pwb, nullptr, geluG, xhb, nullptr, nullptr, nullptr,
      MM, NPROJ, DIMX, NPROJ / BN);

  // conv: xhb -> xch (fp16), 4 t-steps per thread (row reuse)
  k_conv<<<blocks((long)(MM / 4) * HB8), THR, 0, stream>>>(xhb, conv_w, conv_b, xch);

  // fused GEMM2+3: B = [gp_w; ip_w], N = 3072
  //   cols < HID  -> s   = 8*softplus(fl)*sigmoid(. + gp_b) -> sbuf (d_out)
  //   cols >= HID -> inp = sigmoid(. + ip_b)                -> ibuf
  k_gemm<5><<<dim3((MM / BM) * (NPROJ / BN)), 512, 0, stream>>>(
      xch, gwb, nullptr, sbuf, ibuf, gp_b, ip_b, fl,
      MM, NPROJ, HID, NPROJ / BN);

  // scan (xbeta computed on the fly from s, inp, xc)
  k_scan1<<<blocks((long)BB * NC * HB8), THR, 0, stream>>>(sbuf, ibuf, xch, Ac, Bc);
  k_scan2<<<blocks(BB * HID), THR, 0, stream>>>(Ac, Bc, carry);
  k_scan3<<<blocks((long)BB * NC * HB8), THR, 0, stream>>>(sbuf, ibuf, xch, carry, geluG, xhb);

  // GEMM4: out = vb @ out_w^T (plain fp32; overwrites all d_out aliases)
  k_gemm<4><<<dim3((MM / BM) * (DIMX / BN)), 512, 0, stream>>>(
      xhb, owb, out, nullptr, nullptr, nullptr, nullptr, nullptr,
      MM, DIMX, HID, DIMX / BN);
}

// Round 19
// 521.933 us; speedup vs baseline: 1.2197x; 1.2197x over previous
//
#include <hip/hip_runtime.h>
#include <cstdint>
#include <cstddef>

#define DIMX 1024
#define HID  1536
#define BB   4
#define TT   4096
#define MM   (BB*TT)       // 16384 rows
#define NPROJ (2*HID)      // 3072
#define NC   256           // scan chunks
#define CH   16            // chunk length (NC*CH == TT)
#define HB8  (HID/8)       // 192

typedef _Float16 f16x8 __attribute__((ext_vector_type(8)));
typedef float    f32x4 __attribute__((ext_vector_type(4)));

#define GLOAD_LDS16(g, l) \
  __builtin_amdgcn_global_load_lds((__attribute__((address_space(1))) const void*)(g), \
                                   (__attribute__((address_space(3))) void*)(l), 16, 0, 0)

__device__ __forceinline__ float fast_sigmoid(float z) {
  return 1.f / (1.f + __expf(-z));
}
__device__ __forceinline__ float fast_erf(float x) {
  float ax = fabsf(x);
  float t = 1.f / (1.f + 0.3275911f * ax);
  float p = t * (0.254829592f + t * (-0.284496736f + t * (1.421413741f +
            t * (-1.453152027f + t * 1.061405429f))));
  float r = 1.f - p * __expf(-ax * ax);
  return copysignf(r, x);
}

// ------- fused convert fp32 -> fp16 for all 5 tensors, one dispatch -------
__global__ void k_cvt_all(const float* __restrict__ x,  const float* __restrict__ pw,
                          const float* __restrict__ gw, const float* __restrict__ iw,
                          const float* __restrict__ ow,
                          _Float16* __restrict__ xb, _Float16* __restrict__ pwb,
                          _Float16* __restrict__ gwb, _Float16* __restrict__ owb) {
  long i = (long)blockIdx.x * blockDim.x + threadIdx.x;
  const float* src; _Float16* dst; long o;
  if      (i < 4194304) { src = x;  dst = xb;  o = i; }
  else if (i < 4980736) { src = pw; dst = pwb; o = i - 4194304; }
  else if (i < 5570560) { src = gw; dst = gwb; o = i - 4980736; }
  else if (i < 6160384) { src = iw; dst = gwb + 2359296; o = i - 5570560; }
  else if (i < 6553600) { src = ow; dst = owb; o = i - 6160384; }
  else return;
  float4 v = ((const float4*)src)[o];
  union { _Float16 h[4]; uint64_t u; } r;
  r.h[0] = (_Float16)v.x; r.h[1] = (_Float16)v.y;
  r.h[2] = (_Float16)v.z; r.h[3] = (_Float16)v.w;
  ((uint64_t*)dst)[o] = r.u;
}

// ---------------- GEMM: C[M,N] = A[M,K] * B[N,K]^T, fp16 in ----------
// r14 proven core: 128x128 tile, BK=64, 4 waves (2x2),
// double-buffered LDS (64KB, 2 blocks/CU) + T4 counted vmcnt:
//   ds_read buf[cur]; lgkm0; s_barrier;      (reads done, all waves)
//   stage(t+2 -> buf[cur]);                   (race-free overwrite)
//   MFMA; vmcnt(8); s_barrier;                (t+1 landed+visible)
// r13 two-level L2 map: XCD band, G=8 M-tiles sweep N (FETCH 324->148MB).
// T2 LDS XOR swizzle (linear LDS dest, inverse-swizzled global source,
// swizzled read; measured conflicts = 0).
// MODE 1: col<HID -> gelu -> Ch; col>=HID -> raw fp16 -> Ch2
// MODE 5: col<HID -> s = 8*softplus(fl)*sigmoid(v+bias) -> Ch;
//         col>=HID -> inp = sigmoid(v+bias2)            -> Ch2
// MODE 4: plain fp32 -> Cf
#define BM 128
#define BN 128
#define BK 64
#define GRP 8

template<int MODE>
__global__ __launch_bounds__(256) void k_gemm(
    const _Float16* __restrict__ A, const _Float16* __restrict__ B,
    float* __restrict__ Cf, _Float16* __restrict__ Ch, _Float16* __restrict__ Ch2,
    const float* __restrict__ bias, const float* __restrict__ bias2,
    const float* __restrict__ fl,
    int M, int N, int K, int gridN)
{
  __shared__ __align__(16) _Float16 sA[2][BM * BK];   // 2 x 16 KB
  __shared__ __align__(16) _Float16 sB[2][BN * BK];   // 2 x 16 KB (64 KB total)
  const int tid  = threadIdx.x;
  const int wave = tid >> 6;
  const int lane = tid & 63;
  const int wr = wave >> 1, wc = wave & 1;

  // two-level swizzle: XCD band + G-group sweep (bijective for our shapes)
  const int nwg = gridDim.x;
  const int bid = blockIdx.x;
  const int xcd = bid & 7;
  const int loc = bid >> 3;
  const int rpx = (nwg >> 3) / gridN;        // M-tiles per XCD band (=16)
  const int sg  = loc / (GRP * gridN);
  const int rem = loc % (GRP * gridN);
  const int mg  = rem % GRP;                 // m fast
  const int nn  = rem / GRP;                 // n slow
  const long rowA = (long)(xcd * rpx + sg * GRP + mg) * BM;
  const long rowB = (long)nn * BN;

  const int r8  = lane >> 3;
  const int gsw = ((lane & 7) ^ r8) * 8;     // inverse-swizzled source granule

  const int frow = lane & 15;
  const int pg0  = ((lane >> 4) ^ (frow & 7)) << 4;  // swizzled read granule kk=0
  const int pg1  = pg0 ^ 64;                         // kk=1

  auto stage = [&](int buf, int kt) {
    #pragma unroll
    for (int j = 0; j < 4; ++j) {
      const int ck = wave * 4 + j;           // 16 chunks of 8 rows x 64 cols
      const _Float16* ga = A + (rowA + ck * 8 + r8) * (long)K + kt + gsw;
      const _Float16* gb = B + (rowB + ck * 8 + r8) * (long)K + kt + gsw;
      GLOAD_LDS16(ga, &sA[buf][ck * 512]);
      GLOAD_LDS16(gb, &sB[buf][ck * 512]);
    }
  };

  f32x4 acc[4][4] = {};
  const int nt = K / BK;   // 16 or 24

  // prologue: 2 tiles in flight (16 loads); wait tile0 (8 newest remain)
  stage(0, 0);
  stage(1, BK);
  asm volatile("s_waitcnt vmcnt(8)" ::: "memory");
  __builtin_amdgcn_s_barrier();
  __builtin_amdgcn_sched_barrier(0);

  for (int t = 0; t < nt; ++t) {
    const int cur = t & 1;
    const char* sa = (const char*)sA[cur];
    const char* sb = (const char*)sB[cur];

    f16x8 af[4][2], bf[4][2];
    #pragma unroll
    for (int m = 0; m < 4; ++m) {
      const int rb = (wr * 64 + m * 16 + frow) * 128;
      af[m][0] = *(const f16x8*)(sa + rb + pg0);
      af[m][1] = *(const f16x8*)(sa + rb + pg1);
    }
    #pragma unroll
    for (int n = 0; n < 4; ++n) {
      const int rb = (wc * 64 + n * 16 + frow) * 128;
      bf[n][0] = *(const f16x8*)(sb + rb + pg0);
      bf[n][1] = *(const f16x8*)(sb + rb + pg1);
    }
    asm volatile("s_waitcnt lgkmcnt(0)" ::: "memory");   // my reads complete
    __builtin_amdgcn_sched_barrier(0);
    __builtin_amdgcn_s_barrier();                        // all waves' reads complete
    __builtin_amdgcn_sched_barrier(0);

    const bool nl = (t + 2 < nt);
    if (nl) stage(cur, (t + 2) * BK);                    // overwrite buf[cur] for t+2

    __builtin_amdgcn_s_setprio(1);
    #pragma unroll
    for (int kk = 0; kk < 2; ++kk)
      #pragma unroll
      for (int m = 0; m < 4; ++m)
        #pragma unroll
        for (int n = 0; n < 4; ++n)
          acc[m][n] = __builtin_amdgcn_mfma_f32_16x16x32_f16(af[m][kk], bf[n][kk], acc[m][n], 0, 0, 0);
    __builtin_amdgcn_s_setprio(0);

    if (t + 1 < nt) {
      if (nl) { asm volatile("s_waitcnt vmcnt(8)" ::: "memory"); }  // t+1 landed
      else    { asm volatile("s_waitcnt vmcnt(0)" ::: "memory"); }  // tail drain
      __builtin_amdgcn_s_barrier();                     // t+1 visible to all waves
      __builtin_amdgcn_sched_barrier(0);
    }
  }

  // ---------------- epilogue (no DMA outstanding) ----------------
  const int crow0 = (lane >> 4) * 4;
  const int ccol  = lane & 15;

  float bn[4], spn[4];
  if (MODE == 5) {
    #pragma unroll
    for (int n = 0; n < 4; ++n) {
      long c = rowB + wc * 64 + n * 16 + ccol;
      if (c < HID) {
        bn[n]  = bias[c];
        spn[n] = 8.f * log1pf(__expf(fl[c]));
      } else {
        bn[n]  = bias2[c - HID];
        spn[n] = 0.f;
      }
    }
  }

  #pragma unroll
  for (int m = 0; m < 4; ++m)
    #pragma unroll
    for (int n = 0; n < 4; ++n) {
      long r0 = rowA + wr * 64 + m * 16 + crow0;
      long c  = rowB + wc * 64 + n * 16 + ccol;
      #pragma unroll
      for (int r = 0; r < 4; ++r) {
        float v = acc[m][n][r];
        long rr = r0 + r;
        if (MODE == 1) {
          if (c < HID) {
            float ge = 0.5f * v * (1.f + fast_erf(v * 0.70710678118654752f));
            Ch[rr * (long)HID + c] = (_Float16)ge;
          } else {
            Ch2[rr * (long)HID + (c - HID)] = (_Float16)v;
          }
        } else if (MODE == 5) {
          float sig = fast_sigmoid(v + bn[n]);
          if (c < HID) Ch[rr * (long)HID + c] = (_Float16)(spn[n] * sig);
          else         Ch2[rr * (long)HID + (c - HID)] = (_Float16)sig;
        } else {
          Cf[rr * (long)N + c] = v;
        }
      }
    }
}

// ------- depthwise causal conv K=4: 4 t-steps x 8 channels per thread -----
// Row-reuse: 7 row-loads produce 4 outputs (was 4 loads per 1 output).
// TT % 4 == 0 so a 4-row group never crosses a batch boundary.
__global__ void k_conv(const _Float16* __restrict__ xhb, const float* __restrict__ cw,
                       const float* __restrict__ cb, _Float16* __restrict__ xch) {
  long i = (long)blockIdx.x * blockDim.x + threadIdx.x;   // over (MM/4)*HB8
  if (i >= (long)(MM / 4) * HB8) return;
  const int hb = (int)(i % HB8);
  const long m4 = i / HB8;
  const long m0 = m4 * 4;
  const int t0 = (int)(m0 % TT);
  const int h0 = hb * 8;

  f16x8 rows[7];
  #pragma unroll
  for (int j = 0; j < 7; ++j) {
    if (t0 + j - 3 >= 0) {
      rows[j] = *(const f16x8*)&xhb[(m0 + j - 3) * (long)HID + h0];
    } else {
      #pragma unroll
      for (int q = 0; q < 8; ++q) rows[j][q] = (_Float16)0.f;
    }
  }
  float wgt[4][8], bias[8];
  #pragma unroll
  for (int q = 0; q < 8; ++q) {
    bias[q] = cb[h0 + q];
    #pragma unroll
    for (int k = 0; k < 4; ++k) wgt[k][q] = cw[(h0 + q) * 4 + k];
  }
  #pragma unroll
  for (int tt = 0; tt < 4; ++tt) {
    f16x8 o;
    #pragma unroll
    for (int q = 0; q < 8; ++q) {
      float acc = bias[q];
      #pragma unroll
      for (int k = 0; k < 4; ++k) acc += (float)rows[tt + k][q] * wgt[k][q];
      o[q] = (_Float16)acc;
    }
    *(f16x8*)&xch[(m0 + tt) * (long)HID + h0] = o;
  }
}

// ---------------- scan phase 1: per-chunk aggregates, 8 ch/thread ------
// a = exp(-s);  x = sqrt(1-a^2+1e-6)*inp*xc
__global__ void k_scan1(const _Float16* __restrict__ sbuf, const _Float16* __restrict__ ibuf,
                        const _Float16* __restrict__ xcv,
                        float* __restrict__ Ac, float* __restrict__ Bc) {
  long i = (long)blockIdx.x * blockDim.x + threadIdx.x;   // over BB*NC*HB8
  if (i >= (long)BB * NC * HB8) return;
  const int hb = (int)(i % HB8);
  const long bc = i / HB8;
  const int c = (int)(bc % NC);
  const int b = (int)(bc / NC);
  const long base = ((long)b * TT + (long)c * CH) * HID + hb * 8;
  float A[8], Bv[8];
  #pragma unroll
  for (int j = 0; j < 8; ++j) { A[j] = 1.f; Bv[j] = 0.f; }
  #pragma unroll 4
  for (int t = 0; t < CH; ++t) {
    long idx = base + (long)t * HID;
    f16x8 sv = *(const f16x8*)&sbuf[idx];
    f16x8 iv = *(const f16x8*)&ibuf[idx];
    f16x8 xv = *(const f16x8*)&xcv[idx];
    #pragma unroll
    for (int j = 0; j < 8; ++j) {
      float a = __expf(-(float)sv[j]);
      float beta = sqrtf(1.f - a * a + 1e-6f);
      float x = beta * (float)iv[j] * (float)xv[j];
      A[j] *= a;
      Bv[j] = a * Bv[j] + x;
    }
  }
  long o = ((long)b * NC + c) * HID + hb * 8;
  #pragma unroll
  for (int j = 0; j < 8; ++j) { Ac[o + j] = A[j]; Bc[o + j] = Bv[j]; }
}

// ---------------- scan phase 2: prefix over chunks ---------------------
__global__ void k_scan2(const float* __restrict__ Ac, const float* __restrict__ Bc,
                        float* __restrict__ carry) {
  int i = blockIdx.x * blockDim.x + threadIdx.x;          // over BB*HID
  if (i >= BB * HID) return;
  const int h = i % HID;
  const int b = i / HID;
  float cv = 0.f;
  #pragma unroll 8
  for (int c = 0; c < NC; ++c) {
    long idx = ((long)b * NC + c) * HID + h;
    carry[idx] = cv;
    cv = Ac[idx] * cv + Bc[idx];
  }
}

// -------- scan phase 3 + gelu-gate multiply, 8 ch/thread ----------------
__global__ void k_scan3(const _Float16* __restrict__ sbuf, const _Float16* __restrict__ ibuf,
                        const _Float16* __restrict__ xcv, const float* __restrict__ carry,
                        const _Float16* __restrict__ geluG, _Float16* __restrict__ vb) {
  long i = (long)blockIdx.x * blockDim.x + threadIdx.x;   // over BB*NC*HB8
  if (i >= (long)BB * NC * HB8) return;
  const int hb = (int)(i % HB8);
  const long bc = i / HB8;
  const int c = (int)(bc % NC);
  const int b = (int)(bc / NC);
  const long base = ((long)b * TT + (long)c * CH) * HID + hb * 8;
  const long o = ((long)b * NC + c) * HID + hb * 8;
  float hv[8];
  #pragma unroll
  for (int j = 0; j < 8; ++j) hv[j] = carry[o + j];
  #pragma unroll 4
  for (int t = 0; t < CH; ++t) {
    long idx = base + (long)t * HID;
    f16x8 sv = *(const f16x8*)&sbuf[idx];
    f16x8 iv = *(const f16x8*)&ibuf[idx];
    f16x8 xv = *(const f16x8*)&xcv[idx];
    f16x8 gv = *(const f16x8*)&geluG[idx];
    f16x8 ov;
    #pragma unroll
    for (int j = 0; j < 8; ++j) {
      float a = __expf(-(float)sv[j]);
      float beta = sqrtf(1.f - a * a + 1e-6f);
      float x = beta * (float)iv[j] * (float)xv[j];
      hv[j] = a * hv[j] + x;
      ov[j] = (_Float16)((float)gv[j] * hv[j]);
    }
    *(f16x8*)&vb[idx] = ov;
  }
}

extern "C" void kernel_launch(void* const* d_in, const int* in_sizes, int n_in,
                              void* d_out, int out_size, void* d_ws, size_t ws_size,
                              hipStream_t stream) {
  const float* x      = (const float*)d_in[0];
  const float* proj_w = (const float*)d_in[1];
  const float* conv_w = (const float*)d_in[2];
  const float* conv_b = (const float*)d_in[3];
  const float* ip_w   = (const float*)d_in[4];
  const float* ip_b   = (const float*)d_in[5];
  const float* gp_w   = (const float*)d_in[6];
  const float* gp_b   = (const float*)d_in[7];
  const float* fl     = (const float*)d_in[8];
  const float* out_w  = (const float*)d_in[9];
  float* out = (float*)d_out;
  (void)in_sizes; (void)n_in; (void)out_size;

  // ---- workspace layout: 239.1 MB (< 261.1 MB proven available) ----
  const size_t SZ_PW   = (size_t)NPROJ * DIMX * 2;        //  6,291,456
  const size_t SZ_GW   = (size_t)NPROJ * HID * 2;         //  9,437,184
  const size_t SZ_OW   = (size_t)DIMX * HID * 2;          //  3,145,728
  const size_t SZ_MH16 = (size_t)MM * HID * 2;            // 50,331,648 (48 MiB)
  const size_t SZ_SC   = (size_t)BB * NC * HID * 4;       //  6,291,456
  const size_t NEED = SZ_PW + SZ_GW + SZ_OW + 4 * SZ_MH16 + 3 * SZ_SC; // 239,075,328
  if (ws_size < NEED) return;

  char* ws = (char*)d_ws;
  _Float16* pwb   = (_Float16*)(ws);                       // proj weights fp16
  _Float16* gwb   = (_Float16*)(ws + SZ_PW);               // [gp;ip] weights fp16
  _Float16* owb   = (_Float16*)(ws + SZ_PW + SZ_GW);       // out weights fp16
  char* ws2 = ws + SZ_PW + SZ_GW + SZ_OW;
  _Float16* geluG = (_Float16*)(ws2);                      // gelu(gate) fp16
  _Float16* xhb   = (_Float16*)(ws2 + SZ_MH16);            // xh fp16 -> later vb
  _Float16* xch   = (_Float16*)(ws2 + 2 * SZ_MH16);        // conv out fp16 (xc)
  _Float16* ibuf  = (_Float16*)(ws2 + 3 * SZ_MH16);        // inp sigmoid fp16
  float*    Ac    = (float*)(ws2 + 4 * SZ_MH16);
  float*    Bc    = (float*)(ws2 + 4 * SZ_MH16 + SZ_SC);
  float*    carry = (float*)(ws2 + 4 * SZ_MH16 + 2 * SZ_SC);

  // d_out aliasing (64 MiB): xb fp16 [0,32M) dead after GEMM1;
  // sbuf fp16 [0,48M) live GEMM5..scan3; GEMM4 overwrites all of d_out last.
  _Float16* xb    = (_Float16*)d_out;
  _Float16* sbuf  = (_Float16*)d_out;                      // s = 8*softplus*rec

  const int THR = 256;
  auto blocks = [&](long n) { return dim3((unsigned)((n + THR - 1) / THR)); };

  // one fused convert: x, proj_w, gp_w, ip_w, out_w -> fp16
  k_cvt_all<<<dim3(25600), THR, 0, stream>>>(x, proj_w, gp_w, ip_w, out_w,
                                             xb, pwb, gwb, owb);

  // GEMM1: [M,3072] = xb @ proj_w^T ; epilogue: gelu(gate) / raw xh split
  k_gemm<1><<<dim3((MM / BM) * (NPROJ / BN)), 256, 0, stream>>>(
      xb, pwb, nullptr, geluG, xhb, nullptr, nullptr, nullptr,
      MM, NPROJ, DIMX, NPROJ / BN);

  // conv: xhb -> xch (fp16), 4 t-steps per thread (row reuse)
  k_conv<<<blocks((long)(MM / 4) * HB8), THR, 0, stream>>>(xhb, conv_w, conv_b, xch);

  // fused GEMM2+3: B = [gp_w; ip_w], N = 3072
  //   cols < HID  -> s   = 8*softplus(fl)*sigmoid(. + gp_b) -> sbuf (d_out)
  //   cols >= HID -> inp = sigmoid(. + ip_b)                -> ibuf
  k_gemm<5><<<dim3((MM / BM) * (NPROJ / BN)), 256, 0, stream>>>(
      xch, gwb, nullptr, sbuf, ibuf, gp_b, ip_b, fl,
      MM, NPROJ, HID, NPROJ / BN);

  // scan (xbeta computed on the fly from s, inp, xc)
  k_scan1<<<blocks((long)BB * NC * HB8), THR, 0, stream>>>(sbuf, ibuf, xch, Ac, Bc);
  k_scan2<<<blocks(BB * HID), THR, 0, stream>>>(Ac, Bc, carry);
  k_scan3<<<blocks((long)BB * NC * HB8), THR, 0, stream>>>(sbuf, ibuf, xch, carry, geluG, xhb);

  // GEMM4: out = vb @ out_w^T (plain fp32; overwrites all d_out aliases)
  k_gemm<4><<<dim3((MM / BM) * (DIMX / BN)), 256, 0, stream>>>(
      xhb, owb, out, nullptr, nullptr, nullptr, nullptr, nullptr,
      MM, DIMX, HID, DIMX / BN);
}